// Round 2
// baseline (559.094 us; speedup 1.0000x reference)
//
#include <hip/hip_runtime.h>
#include <hip/hip_bf16.h>

#define LEAKY_SLOPE 0.2f

__device__ __forceinline__ float leaky(float x) { return x > 0.f ? x : LEAKY_SLOPE * x; }

// ---------------------------------------------------------------------------
// GEMM: h1 = x @ W1  (n x 128 @ 128 x 128), plus per-node alpha_src/alpha_dst
// h1 stored swizzled: [node][ch(64)][head(2)]  (pos p = c*2 + head)
// alpha stored as float2 {head0, head1} per node.
// ---------------------------------------------------------------------------
__global__ __launch_bounds__(256) void gemm1_kernel(
    const float* __restrict__ x, const float* __restrict__ W1,
    const float* __restrict__ a_s, const float* __restrict__ a_d,
    float* __restrict__ h1, float2* __restrict__ as1, float2* __restrict__ ad1, int n)
{
    __shared__ float wlds[128 * 128];   // 64 KB, swizzled columns
    int tid = threadIdx.x;
    // stage W1 swizzled: col j -> p = (j&63)*2 + (j>>6)
    for (int i = tid; i < 128 * 128; i += 256) {
        int k = i >> 7, j = i & 127;
        wlds[(k << 7) + ((j & 63) * 2 + (j >> 6))] = W1[i];
    }
    int l  = tid & 31;   // lane within 32-group
    int g  = tid >> 5;   // group 0..7 -> node offset within block-iter
    int p0 = l * 4;      // swizzled column base for this thread
    float aS[4], aD[4];
#pragma unroll
    for (int i = 0; i < 4; ++i) {
        int p = p0 + i;
        int j = ((p & 1) << 6) + (p >> 1);   // unswizzle
        aS[i] = a_s[j];
        aD[i] = a_d[j];
    }
    __syncthreads();
    int lane = tid & 63;

    for (int base = blockIdx.x * 8; base < n; base += gridDim.x * 8) {
        int node = base + g;
        bool valid = node < n;
        float4 xr = make_float4(0.f, 0.f, 0.f, 0.f);
        if (valid) xr = *(const float4*)(x + (size_t)node * 128 + l * 4);
        float acc0 = 0.f, acc1 = 0.f, acc2 = 0.f, acc3 = 0.f;
#pragma unroll 8
        for (int k4 = 0; k4 < 32; ++k4) {
            int srcl = k4 + (lane & 32);
            float x0 = __shfl(xr.x, srcl);
            float x1 = __shfl(xr.y, srcl);
            float x2 = __shfl(xr.z, srcl);
            float x3 = __shfl(xr.w, srcl);
            const float4 w0 = *(const float4*)&wlds[(k4 * 4 + 0) * 128 + p0];
            const float4 w1 = *(const float4*)&wlds[(k4 * 4 + 1) * 128 + p0];
            const float4 w2 = *(const float4*)&wlds[(k4 * 4 + 2) * 128 + p0];
            const float4 w3 = *(const float4*)&wlds[(k4 * 4 + 3) * 128 + p0];
            acc0 = fmaf(x0, w0.x, acc0); acc1 = fmaf(x0, w0.y, acc1);
            acc2 = fmaf(x0, w0.z, acc2); acc3 = fmaf(x0, w0.w, acc3);
            acc0 = fmaf(x1, w1.x, acc0); acc1 = fmaf(x1, w1.y, acc1);
            acc2 = fmaf(x1, w1.z, acc2); acc3 = fmaf(x1, w1.w, acc3);
            acc0 = fmaf(x2, w2.x, acc0); acc1 = fmaf(x2, w2.y, acc1);
            acc2 = fmaf(x2, w2.z, acc2); acc3 = fmaf(x2, w2.w, acc3);
            acc0 = fmaf(x3, w3.x, acc0); acc1 = fmaf(x3, w3.y, acc1);
            acc2 = fmaf(x3, w3.z, acc2); acc3 = fmaf(x3, w3.w, acc3);
        }
        if (valid) {
            *(float4*)&h1[(size_t)node * 128 + p0] = make_float4(acc0, acc1, acc2, acc3);
            // alpha reductions (head-separated):
            float vs0 = acc0 * aS[0] + acc2 * aS[2];   // head0
            float vs1 = acc1 * aS[1] + acc3 * aS[3];   // head1
            float vd0 = acc0 * aD[0] + acc2 * aD[2];
            float vd1 = acc1 * aD[1] + acc3 * aD[3];
#pragma unroll
            for (int off = 1; off < 32; off <<= 1) {
                vs0 += __shfl_xor(vs0, off);
                vs1 += __shfl_xor(vs1, off);
                vd0 += __shfl_xor(vd0, off);
                vd1 += __shfl_xor(vd1, off);
            }
            if (l == 0) {
                as1[node] = make_float2(vs0, vs1);
                ad1[node] = make_float2(vd0, vd1);
            }
        }
    }
}

// ---------------------------------------------------------------------------
// CSR build: histogram -> scan (3 kernels) -> scatter
// ---------------------------------------------------------------------------
__global__ void hist_kernel(const int* __restrict__ dst, int* __restrict__ deg, int E)
{
    int e = blockIdx.x * 256 + threadIdx.x;
    if (e < E) atomicAdd(&deg[dst[e]], 1);
}

__global__ __launch_bounds__(256) void scan1_kernel(const int* __restrict__ deg, int n,
                                                    int* __restrict__ lscan, int* __restrict__ bsums)
{
    __shared__ int warp_sums[4];
    int tid = threadIdx.x;
    int base = blockIdx.x * 1024;
    int idx = base + tid * 4;
    int v0 = (idx + 0 < n) ? deg[idx + 0] : 0;
    int v1 = (idx + 1 < n) ? deg[idx + 1] : 0;
    int v2 = (idx + 2 < n) ? deg[idx + 2] : 0;
    int v3 = (idx + 3 < n) ? deg[idx + 3] : 0;
    int tsum = v0 + v1 + v2 + v3;
    int lane = tid & 63;
    int incl = tsum;
#pragma unroll
    for (int off = 1; off < 64; off <<= 1) {
        int t = __shfl_up(incl, off);
        if (lane >= off) incl += t;
    }
    int wid = tid >> 6;
    if (lane == 63) warp_sums[wid] = incl;
    __syncthreads();
    int wbase = 0;
    for (int w = 0; w < wid; ++w) wbase += warp_sums[w];
    int run = wbase + incl - tsum;   // exclusive prefix for first element
    if (idx + 0 < n) lscan[idx + 0] = run; run += v0;
    if (idx + 1 < n) lscan[idx + 1] = run; run += v1;
    if (idx + 2 < n) lscan[idx + 2] = run; run += v2;
    if (idx + 3 < n) lscan[idx + 3] = run;
    if (tid == 255) bsums[blockIdx.x] = wbase + incl;
}

__global__ void scan2_kernel(const int* __restrict__ bsums, int nb, int* __restrict__ bpref)
{
    int lane = threadIdx.x;
    if (nb <= 64) {
        int v = (lane < nb) ? bsums[lane] : 0;
        int incl = v;
#pragma unroll
        for (int off = 1; off < 64; off <<= 1) {
            int t = __shfl_up(incl, off);
            if (lane >= off) incl += t;
        }
        if (lane < nb) bpref[lane] = incl - v;
        if (lane == 63) bpref[nb] = incl;
    } else if (lane == 0) {
        int run = 0;
        for (int i = 0; i < nb; ++i) { bpref[i] = run; run += bsums[i]; }
        bpref[nb] = run;
    }
}

__global__ void scan3_kernel(const int* __restrict__ lscan, const int* __restrict__ bpref,
                             int n, int nb, int* __restrict__ row_start, int* __restrict__ cursor)
{
    int i = blockIdx.x * 256 + threadIdx.x;
    if (i < n) {
        int r = lscan[i] + bpref[i >> 10];
        row_start[i] = r;
        cursor[i] = r;
    } else if (i == n) {
        row_start[n] = bpref[nb];
    }
}

__global__ void scatter_kernel(const int* __restrict__ src, const int* __restrict__ dst,
                               int* __restrict__ cursor, int* __restrict__ csr_src, int E)
{
    int e = blockIdx.x * 256 + threadIdx.x;
    if (e < E) {
        int p = atomicAdd(&cursor[dst[e]], 1);
        csr_src[p] = src[e];
    }
}

// ---------------------------------------------------------------------------
// Layer-1 gather: one wave per node, online softmax over in-edges (+ self loop).
// Epilogue: bias + relu, then h2 = h_relu . W2 (wave reduce) -> h2[node].
// ---------------------------------------------------------------------------
__global__ __launch_bounds__(256) void gather1_kernel(
    const float* __restrict__ h1, const float2* __restrict__ as1, const float2* __restrict__ ad1,
    const int* __restrict__ row_start, const int* __restrict__ csr_src,
    const float* __restrict__ b1, const float* __restrict__ W2,
    float* __restrict__ h2, int n)
{
    int wid = threadIdx.x >> 6, lane = threadIdx.x & 63;
    int v = blockIdx.x * 4 + wid;
    if (v >= n) return;

    float2 ad = ad1[v];
    float2 asv = as1[v];
    float e0 = leaky(asv.x + ad.x), e1 = leaky(asv.y + ad.y);
    float m0 = e0, m1 = e1, s0 = 1.f, s1 = 1.f;
    const float2* hrow = (const float2*)h1;     // [node][64] of {head0,head1}
    float2 hs = hrow[(size_t)v * 64 + lane];
    float acc0 = hs.x, acc1 = hs.y;             // self loop, weight exp(0)=1

    int t1 = row_start[v + 1];
    for (int t = row_start[v]; t < t1; ++t) {
        int srcn = csr_src[t];
        float2 as = as1[srcn];
        float e0n = leaky(as.x + ad.x), e1n = leaky(as.y + ad.y);
        hs = hrow[(size_t)srcn * 64 + lane];
        if (e0n > m0) { float c = __expf(m0 - e0n); s0 *= c; acc0 *= c; m0 = e0n; }
        if (e1n > m1) { float c = __expf(m1 - e1n); s1 *= c; acc1 *= c; m1 = e1n; }
        float p0 = __expf(e0n - m0), p1 = __expf(e1n - m1);
        s0 += p0; s1 += p1;
        acc0 = fmaf(p0, hs.x, acc0);
        acc1 = fmaf(p1, hs.y, acc1);
    }
    float o0 = acc0 / (s0 + 1e-16f) + b1[lane];        // feature lane   (head0)
    float o1 = acc1 / (s1 + 1e-16f) + b1[64 + lane];   // feature 64+lane (head1)
    o0 = fmaxf(o0, 0.f);
    o1 = fmaxf(o1, 0.f);
    float hv = o0 * W2[lane] + o1 * W2[64 + lane];
#pragma unroll
    for (int off = 1; off < 64; off <<= 1) hv += __shfl_xor(hv, off);
    if (lane == 0) h2[v] = hv;
}

// ---------------------------------------------------------------------------
// Layer-2 gather: one thread per node (scalar head), online softmax + sigmoid.
// ---------------------------------------------------------------------------
__global__ void gather2_kernel(
    const float* __restrict__ h2, const int* __restrict__ row_start, const int* __restrict__ csr_src,
    const float* __restrict__ aS2, const float* __restrict__ aD2, const float* __restrict__ b2,
    float* __restrict__ out, int n)
{
    int v = blockIdx.x * 256 + threadIdx.x;
    if (v >= n) return;
    float as2 = aS2[0], ad2c = aD2[0];
    float hv = h2[v];
    float ad = hv * ad2c;
    float e = leaky(hv * as2 + ad);
    float m = e, s = 1.f, num = hv;
    int t1 = row_start[v + 1];
    for (int t = row_start[v]; t < t1; ++t) {
        int srcn = csr_src[t];
        float hsv = h2[srcn];
        float en = leaky(hsv * as2 + ad);
        if (en > m) { float c = __expf(m - en); s *= c; num *= c; m = en; }
        float p = __expf(en - m);
        s += p;
        num = fmaf(p, hsv, num);
    }
    float o = num / (s + 1e-16f) + b2[0];
    out[v] = 1.f / (1.f + __expf(-o));
}

// ---------------------------------------------------------------------------
extern "C" void kernel_launch(void* const* d_in, const int* in_sizes, int n_in,
                              void* d_out, int out_size, void* d_ws, size_t ws_size,
                              hipStream_t stream)
{
    const float* x      = (const float*)d_in[0];
    const int*   eidx   = (const int*)  d_in[1];
    const float* W1     = (const float*)d_in[2];
    const float* a_src1 = (const float*)d_in[3];
    const float* a_dst1 = (const float*)d_in[4];
    const float* b1     = (const float*)d_in[5];
    const float* W2     = (const float*)d_in[6];
    const float* a_src2 = (const float*)d_in[7];
    const float* a_dst2 = (const float*)d_in[8];
    const float* b2     = (const float*)d_in[9];

    int n = in_sizes[0] / 128;
    int E = in_sizes[1] / 2;
    const int* src = eidx;
    const int* dst = eidx + E;

    char* ws = (char*)d_ws;
    size_t off = 0;
    auto alloc = [&](size_t bytes) { size_t o = off; off += (bytes + 255) & ~(size_t)255; return o; };

    float*  h1      = (float*) (ws + alloc((size_t)n * 128 * 4));
    float2* as1     = (float2*)(ws + alloc((size_t)n * 8));
    float2* ad1     = (float2*)(ws + alloc((size_t)n * 8));
    float*  h2      = (float*) (ws + alloc((size_t)n * 4));
    int*    deg     = (int*)   (ws + alloc((size_t)n * 4));
    int*    lscan   = (int*)   (ws + alloc((size_t)n * 4));
    int*    rowst   = (int*)   (ws + alloc((size_t)(n + 1) * 4));
    int*    cursor  = (int*)   (ws + alloc((size_t)n * 4));
    int*    bsums   = (int*)   (ws + alloc(64 * 4));
    int*    bpref   = (int*)   (ws + alloc(65 * 4));
    int*    csr_src = (int*)   (ws + alloc((size_t)E * 4));
    (void)ws_size; (void)n_in; (void)out_size;

    hipMemsetAsync(deg, 0, (size_t)n * 4, stream);

    gemm1_kernel<<<1024, 256, 0, stream>>>(x, W1, a_src1, a_dst1, h1, as1, ad1, n);

    hist_kernel<<<(E + 255) / 256, 256, 0, stream>>>(dst, deg, E);
    int nb = (n + 1023) / 1024;
    scan1_kernel<<<nb, 256, 0, stream>>>(deg, n, lscan, bsums);
    scan2_kernel<<<1, 64, 0, stream>>>(bsums, nb, bpref);
    scan3_kernel<<<(n + 1 + 255) / 256, 256, 0, stream>>>(lscan, bpref, n, nb, rowst, cursor);
    scatter_kernel<<<(E + 255) / 256, 256, 0, stream>>>(src, dst, cursor, csr_src, E);

    gather1_kernel<<<(n + 3) / 4, 256, 0, stream>>>(h1, as1, ad1, rowst, csr_src, b1, W2, h2, n);
    gather2_kernel<<<(n + 255) / 256, 256, 0, stream>>>(h2, rowst, csr_src, a_src2, a_dst2, b2,
                                                        (float*)d_out, n);
}

// Round 5
// 479.424 us; speedup vs baseline: 1.1662x; 1.1662x over previous
//
#include <hip/hip_runtime.h>
#include <hip/hip_bf16.h>

#define LEAKY_SLOPE 0.2f

__device__ __forceinline__ float leaky(float x) { return x > 0.f ? x : LEAKY_SLOPE * x; }

// round-to-nearest-even bf16 packing: lo -> low 16 bits, hi -> high 16 bits
__device__ __forceinline__ unsigned pack_bf16_pair(float lo, float hi)
{
    unsigned bl = __float_as_uint(lo);
    bl = (bl + 0x7fffu + ((bl >> 16) & 1u)) >> 16;
    unsigned bh = __float_as_uint(hi);
    bh = (bh + 0x7fffu + ((bh >> 16) & 1u)) & 0xffff0000u;
    return bl | bh;
}

// ---------------------------------------------------------------------------
// GEMM: h1 = x @ W1  (n x 128 @ 128 x 128), plus per-node alpha_src/alpha_dst
// h1 stored bf16-packed: h1b[node*64 + c] = {head0 low16, head1 high16} for channel c
// alpha stored as float2 {head0, head1} per node (f32 — attention logits stay exact).
// ---------------------------------------------------------------------------
__global__ __launch_bounds__(256) void gemm1_kernel(
    const float* __restrict__ x, const float* __restrict__ W1,
    const float* __restrict__ a_s, const float* __restrict__ a_d,
    unsigned* __restrict__ h1b, float2* __restrict__ as1, float2* __restrict__ ad1, int n)
{
    __shared__ float wlds[128 * 128];   // 64 KB, swizzled columns
    int tid = threadIdx.x;
    // stage W1 swizzled: col j -> p = (j&63)*2 + (j>>6)  (p = channel*2 + head)
    for (int i = tid; i < 128 * 128; i += 256) {
        int k = i >> 7, j = i & 127;
        wlds[(k << 7) + ((j & 63) * 2 + (j >> 6))] = W1[i];
    }
    int l  = tid & 31;   // lane within 32-group
    int g  = tid >> 5;   // group 0..7 -> node offset within block-iter
    int p0 = l * 4;      // swizzled column base for this thread
    float aS[4], aD[4];
#pragma unroll
    for (int i = 0; i < 4; ++i) {
        int p = p0 + i;
        int j = ((p & 1) << 6) + (p >> 1);   // unswizzle
        aS[i] = a_s[j];
        aD[i] = a_d[j];
    }
    __syncthreads();
    int lane = tid & 63;

    for (int base = blockIdx.x * 8; base < n; base += gridDim.x * 8) {
        int node = base + g;
        bool valid = node < n;
        float4 xr = make_float4(0.f, 0.f, 0.f, 0.f);
        if (valid) xr = *(const float4*)(x + (size_t)node * 128 + l * 4);
        float acc0 = 0.f, acc1 = 0.f, acc2 = 0.f, acc3 = 0.f;
#pragma unroll 8
        for (int k4 = 0; k4 < 32; ++k4) {
            int srcl = k4 + (lane & 32);
            float x0 = __shfl(xr.x, srcl);
            float x1 = __shfl(xr.y, srcl);
            float x2 = __shfl(xr.z, srcl);
            float x3 = __shfl(xr.w, srcl);
            const float4 w0 = *(const float4*)&wlds[(k4 * 4 + 0) * 128 + p0];
            const float4 w1 = *(const float4*)&wlds[(k4 * 4 + 1) * 128 + p0];
            const float4 w2 = *(const float4*)&wlds[(k4 * 4 + 2) * 128 + p0];
            const float4 w3 = *(const float4*)&wlds[(k4 * 4 + 3) * 128 + p0];
            acc0 = fmaf(x0, w0.x, acc0); acc1 = fmaf(x0, w0.y, acc1);
            acc2 = fmaf(x0, w0.z, acc2); acc3 = fmaf(x0, w0.w, acc3);
            acc0 = fmaf(x1, w1.x, acc0); acc1 = fmaf(x1, w1.y, acc1);
            acc2 = fmaf(x1, w1.z, acc2); acc3 = fmaf(x1, w1.w, acc3);
            acc0 = fmaf(x2, w2.x, acc0); acc1 = fmaf(x2, w2.y, acc1);
            acc2 = fmaf(x2, w2.z, acc2); acc3 = fmaf(x2, w2.w, acc3);
            acc0 = fmaf(x3, w3.x, acc0); acc1 = fmaf(x3, w3.y, acc1);
            acc2 = fmaf(x3, w3.z, acc2); acc3 = fmaf(x3, w3.w, acc3);
        }
        if (valid) {
            // acc0=(ch 2l, h0) acc1=(ch 2l, h1) acc2=(ch 2l+1, h0) acc3=(ch 2l+1, h1)
            unsigned u0 = pack_bf16_pair(acc0, acc1);
            unsigned u1 = pack_bf16_pair(acc2, acc3);
            *(uint2*)&h1b[(size_t)node * 64 + 2 * l] = make_uint2(u0, u1);
            // alpha reductions (head-separated), on exact f32 accumulators:
            float vs0 = acc0 * aS[0] + acc2 * aS[2];   // head0
            float vs1 = acc1 * aS[1] + acc3 * aS[3];   // head1
            float vd0 = acc0 * aD[0] + acc2 * aD[2];
            float vd1 = acc1 * aD[1] + acc3 * aD[3];
#pragma unroll
            for (int off = 1; off < 32; off <<= 1) {
                vs0 += __shfl_xor(vs0, off);
                vs1 += __shfl_xor(vs1, off);
                vd0 += __shfl_xor(vd0, off);
                vd1 += __shfl_xor(vd1, off);
            }
            if (l == 0) {
                as1[node] = make_float2(vs0, vs1);
                ad1[node] = make_float2(vd0, vd1);
            }
        }
    }
}

// ---------------------------------------------------------------------------
// CSR build: histogram -> scan (3 kernels) -> scatter
// ---------------------------------------------------------------------------
__global__ void hist_kernel(const int* __restrict__ dst, int* __restrict__ deg, int E)
{
    int e = blockIdx.x * 256 + threadIdx.x;
    if (e < E) atomicAdd(&deg[dst[e]], 1);
}

__global__ __launch_bounds__(256) void scan1_kernel(const int* __restrict__ deg, int n,
                                                    int* __restrict__ lscan, int* __restrict__ bsums)
{
    __shared__ int warp_sums[4];
    int tid = threadIdx.x;
    int base = blockIdx.x * 1024;
    int idx = base + tid * 4;
    int v0 = (idx + 0 < n) ? deg[idx + 0] : 0;
    int v1 = (idx + 1 < n) ? deg[idx + 1] : 0;
    int v2 = (idx + 2 < n) ? deg[idx + 2] : 0;
    int v3 = (idx + 3 < n) ? deg[idx + 3] : 0;
    int tsum = v0 + v1 + v2 + v3;
    int lane = tid & 63;
    int incl = tsum;
#pragma unroll
    for (int off = 1; off < 64; off <<= 1) {
        int t = __shfl_up(incl, off);
        if (lane >= off) incl += t;
    }
    int wid = tid >> 6;
    if (lane == 63) warp_sums[wid] = incl;
    __syncthreads();
    int wbase = 0;
    for (int w = 0; w < wid; ++w) wbase += warp_sums[w];
    int run = wbase + incl - tsum;   // exclusive prefix for first element
    if (idx + 0 < n) lscan[idx + 0] = run; run += v0;
    if (idx + 1 < n) lscan[idx + 1] = run; run += v1;
    if (idx + 2 < n) lscan[idx + 2] = run; run += v2;
    if (idx + 3 < n) lscan[idx + 3] = run;
    if (tid == 255) bsums[blockIdx.x] = wbase + incl;
}

__global__ void scan2_kernel(const int* __restrict__ bsums, int nb, int* __restrict__ bpref)
{
    int lane = threadIdx.x;
    if (nb <= 64) {
        int v = (lane < nb) ? bsums[lane] : 0;
        int incl = v;
#pragma unroll
        for (int off = 1; off < 64; off <<= 1) {
            int t = __shfl_up(incl, off);
            if (lane >= off) incl += t;
        }
        if (lane < nb) bpref[lane] = incl - v;
        if (lane == 63) bpref[nb] = incl;
    } else if (lane == 0) {
        int run = 0;
        for (int i = 0; i < nb; ++i) { bpref[i] = run; run += bsums[i]; }
        bpref[nb] = run;
    }
}

__global__ void scan3_kernel(const int* __restrict__ lscan, const int* __restrict__ bpref,
                             int n, int nb, int* __restrict__ row_start, int* __restrict__ cursor)
{
    int i = blockIdx.x * 256 + threadIdx.x;
    if (i < n) {
        int r = lscan[i] + bpref[i >> 10];
        row_start[i] = r;
        cursor[i] = r;
    } else if (i == n) {
        row_start[n] = bpref[nb];
    }
}

__global__ void scatter_kernel(const int* __restrict__ src, const int* __restrict__ dst,
                               int* __restrict__ cursor, int* __restrict__ csr_src, int E)
{
    int e = blockIdx.x * 256 + threadIdx.x;
    if (e < E) {
        int p = atomicAdd(&cursor[dst[e]], 1);
        csr_src[p] = src[e];
    }
}

// ---------------------------------------------------------------------------
// Layer-1 gather: one wave per node. Chunked online softmax: 64 edges per
// chunk, each lane computes one edge's logit+exp in parallel; shfl reductions
// for chunk max/sum; serial weighted-sum loop is just shfl+load+2 fma.
// Epilogue: bias + relu, then h2 = h_relu . W2 (wave reduce) -> h2[node].
// ---------------------------------------------------------------------------
__global__ __launch_bounds__(256) void gather1_kernel(
    const unsigned* __restrict__ h1b, const float2* __restrict__ as1, const float2* __restrict__ ad1,
    const int* __restrict__ row_start, const int* __restrict__ csr_src,
    const float* __restrict__ b1, const float* __restrict__ W2,
    float* __restrict__ h2, int n)
{
    int wid = threadIdx.x >> 6, lane = threadIdx.x & 63;
    int v = blockIdx.x * 4 + wid;
    if (v >= n) return;

    float2 ad = ad1[v];
    float2 asv = as1[v];
    float m0 = leaky(asv.x + ad.x), m1 = leaky(asv.y + ad.y);   // self-loop logit
    float s0 = 1.f, s1 = 1.f;
    unsigned su = h1b[(size_t)v * 64 + lane];
    float acc0 = __uint_as_float(su << 16);          // head0 (channel = lane)
    float acc1 = __uint_as_float(su & 0xffff0000u);  // head1

    int t0 = row_start[v], t1 = row_start[v + 1];
    for (int t = t0; t < t1; t += 64) {
        int nv = t1 - t; if (nv > 64) nv = 64;
        int srcn = v;
        float e0 = -INFINITY, e1 = -INFINITY;
        if (lane < nv) {
            srcn = csr_src[t + lane];
            float2 as = as1[srcn];
            e0 = leaky(as.x + ad.x);
            e1 = leaky(as.y + ad.y);
        }
        // chunk max (both heads)
        float c0 = e0, c1 = e1;
#pragma unroll
        for (int off = 32; off >= 1; off >>= 1) {
            c0 = fmaxf(c0, __shfl_xor(c0, off));
            c1 = fmaxf(c1, __shfl_xor(c1, off));
        }
        float nm0 = fmaxf(m0, c0), nm1 = fmaxf(m1, c1);
        float r0 = __expf(m0 - nm0), r1 = __expf(m1 - nm1);
        acc0 *= r0; acc1 *= r1; s0 *= r0; s1 *= r1;
        m0 = nm0; m1 = nm1;
        // per-lane edge weight (one exp per lane per head)
        float p0 = __expf(e0 - m0), p1 = __expf(e1 - m1);   // -inf -> 0 for masked lanes
        float q0 = p0, q1 = p1;
#pragma unroll
        for (int off = 32; off >= 1; off >>= 1) {
            q0 += __shfl_xor(q0, off);
            q1 += __shfl_xor(q1, off);
        }
        s0 += q0; s1 += q1;
        // serial weighted gather over the chunk's edges
        for (int j = 0; j < nv; ++j) {
            int sj   = __shfl(srcn, j);
            float w0 = __shfl(p0, j);
            float w1 = __shfl(p1, j);
            unsigned hu = h1b[(size_t)sj * 64 + lane];
            acc0 = fmaf(w0, __uint_as_float(hu << 16), acc0);
            acc1 = fmaf(w1, __uint_as_float(hu & 0xffff0000u), acc1);
        }
    }
    float o0 = acc0 / (s0 + 1e-16f) + b1[lane];        // head0, channel=lane
    float o1 = acc1 / (s1 + 1e-16f) + b1[64 + lane];   // head1
    o0 = fmaxf(o0, 0.f);
    o1 = fmaxf(o1, 0.f);
    float hv = o0 * W2[lane] + o1 * W2[64 + lane];
#pragma unroll
    for (int off = 1; off < 64; off <<= 1) hv += __shfl_xor(hv, off);
    if (lane == 0) h2[v] = hv;
}

// ---------------------------------------------------------------------------
// Layer-2 gather: one thread per node (scalar head), online softmax + sigmoid.
// ---------------------------------------------------------------------------
__global__ void gather2_kernel(
    const float* __restrict__ h2, const int* __restrict__ row_start, const int* __restrict__ csr_src,
    const float* __restrict__ aS2, const float* __restrict__ aD2, const float* __restrict__ b2,
    float* __restrict__ out, int n)
{
    int v = blockIdx.x * 256 + threadIdx.x;
    if (v >= n) return;
    float as2 = aS2[0], ad2c = aD2[0];
    float hv = h2[v];
    float ad = hv * ad2c;
    float e = leaky(hv * as2 + ad);
    float m = e, s = 1.f, num = hv;
    int t1 = row_start[v + 1];
    for (int t = row_start[v]; t < t1; ++t) {
        int srcn = csr_src[t];
        float hsv = h2[srcn];
        float en = leaky(hsv * as2 + ad);
        if (en > m) { float c = __expf(m - en); s *= c; num *= c; m = en; }
        float p = __expf(en - m);
        s += p;
        num = fmaf(p, hsv, num);
    }
    float o = num / (s + 1e-16f) + b2[0];
    out[v] = 1.f / (1.f + __expf(-o));
}

// ---------------------------------------------------------------------------
extern "C" void kernel_launch(void* const* d_in, const int* in_sizes, int n_in,
                              void* d_out, int out_size, void* d_ws, size_t ws_size,
                              hipStream_t stream)
{
    const float* x      = (const float*)d_in[0];
    const int*   eidx   = (const int*)  d_in[1];
    const float* W1     = (const float*)d_in[2];
    const float* a_src1 = (const float*)d_in[3];
    const float* a_dst1 = (const float*)d_in[4];
    const float* b1     = (const float*)d_in[5];
    const float* W2     = (const float*)d_in[6];
    const float* a_src2 = (const float*)d_in[7];
    const float* a_dst2 = (const float*)d_in[8];
    const float* b2     = (const float*)d_in[9];

    int n = in_sizes[0] / 128;
    int E = in_sizes[1] / 2;
    const int* src = eidx;
    const int* dst = eidx + E;

    char* ws = (char*)d_ws;
    size_t off = 0;
    auto alloc = [&](size_t bytes) { size_t o = off; off += (bytes + 255) & ~(size_t)255; return o; };

    unsigned* h1b    = (unsigned*)(ws + alloc((size_t)n * 64 * 4));   // bf16-packed, 12.8 MB
    float2* as1     = (float2*)(ws + alloc((size_t)n * 8));
    float2* ad1     = (float2*)(ws + alloc((size_t)n * 8));
    float*  h2      = (float*) (ws + alloc((size_t)n * 4));
    int*    deg     = (int*)   (ws + alloc((size_t)n * 4));
    int*    lscan   = (int*)   (ws + alloc((size_t)n * 4));
    int*    rowst   = (int*)   (ws + alloc((size_t)(n + 1) * 4));
    int*    cursor  = (int*)   (ws + alloc((size_t)n * 4));
    int*    bsums   = (int*)   (ws + alloc(64 * 4));
    int*    bpref   = (int*)   (ws + alloc(65 * 4));
    int*    csr_src = (int*)   (ws + alloc((size_t)E * 4));
    (void)ws_size; (void)n_in; (void)out_size;

    hipMemsetAsync(deg, 0, (size_t)n * 4, stream);

    gemm1_kernel<<<1024, 256, 0, stream>>>(x, W1, a_src1, a_dst1, h1b, as1, ad1, n);

    hist_kernel<<<(E + 255) / 256, 256, 0, stream>>>(dst, deg, E);
    int nb = (n + 1023) / 1024;
    scan1_kernel<<<nb, 256, 0, stream>>>(deg, n, lscan, bsums);
    scan2_kernel<<<1, 64, 0, stream>>>(bsums, nb, bpref);
    scan3_kernel<<<(n + 1 + 255) / 256, 256, 0, stream>>>(lscan, bpref, n, nb, rowst, cursor);
    scatter_kernel<<<(E + 255) / 256, 256, 0, stream>>>(src, dst, cursor, csr_src, E);

    gather1_kernel<<<(n + 3) / 4, 256, 0, stream>>>(h1b, as1, ad1, rowst, csr_src, b1, W2, h2, n);
    gather2_kernel<<<(n + 255) / 256, 256, 0, stream>>>(h2, rowst, csr_src, a_src2, a_dst2, b2,
                                                        (float*)d_out, n);
}

// Round 7
// 386.279 us; speedup vs baseline: 1.4474x; 1.2411x over previous
//
#include <hip/hip_runtime.h>
#include <hip/hip_bf16.h>

#define LEAKY_SLOPE 0.2f

__device__ __forceinline__ float leaky(float x) { return x > 0.f ? x : LEAKY_SLOPE * x; }

// round-to-nearest-even bf16 packing: lo -> low 16 bits, hi -> high 16 bits
__device__ __forceinline__ unsigned pack_bf16_pair(float lo, float hi)
{
    unsigned bl = __float_as_uint(lo);
    bl = (bl + 0x7fffu + ((bl >> 16) & 1u)) >> 16;
    unsigned bh = __float_as_uint(hi);
    bh = (bh + 0x7fffu + ((bh >> 16) & 1u)) & 0xffff0000u;
    return bl | bh;
}

// ---------------------------------------------------------------------------
// GEMM: h1 = x @ W1  (n x 128 @ 128 x 128), plus per-node alpha_src/alpha_dst
// h1 stored bf16-packed: h1b[node*64 + c] = {head0 low16, head1 high16}
// ---------------------------------------------------------------------------
__global__ __launch_bounds__(256) void gemm1_kernel(
    const float* __restrict__ x, const float* __restrict__ W1,
    const float* __restrict__ a_s, const float* __restrict__ a_d,
    unsigned* __restrict__ h1b, float2* __restrict__ as1, float2* __restrict__ ad1, int n)
{
    __shared__ float wlds[128 * 128];   // 64 KB, swizzled columns
    int tid = threadIdx.x;
    // stage W1 swizzled: col j -> p = (j&63)*2 + (j>>6)  (p = channel*2 + head)
    for (int i = tid; i < 128 * 128; i += 256) {
        int k = i >> 7, j = i & 127;
        wlds[(k << 7) + ((j & 63) * 2 + (j >> 6))] = W1[i];
    }
    int l  = tid & 31;   // lane within 32-group
    int g  = tid >> 5;   // group 0..7 -> node offset within block-iter
    int p0 = l * 4;      // swizzled column base for this thread
    float aS[4], aD[4];
#pragma unroll
    for (int i = 0; i < 4; ++i) {
        int p = p0 + i;
        int j = ((p & 1) << 6) + (p >> 1);   // unswizzle
        aS[i] = a_s[j];
        aD[i] = a_d[j];
    }
    __syncthreads();
    int lane = tid & 63;

    for (int base = blockIdx.x * 8; base < n; base += gridDim.x * 8) {
        int node = base + g;
        bool valid = node < n;
        float4 xr = make_float4(0.f, 0.f, 0.f, 0.f);
        if (valid) xr = *(const float4*)(x + (size_t)node * 128 + l * 4);
        float acc0 = 0.f, acc1 = 0.f, acc2 = 0.f, acc3 = 0.f;
#pragma unroll 8
        for (int k4 = 0; k4 < 32; ++k4) {
            int srcl = k4 + (lane & 32);
            float x0 = __shfl(xr.x, srcl);
            float x1 = __shfl(xr.y, srcl);
            float x2 = __shfl(xr.z, srcl);
            float x3 = __shfl(xr.w, srcl);
            const float4 w0 = *(const float4*)&wlds[(k4 * 4 + 0) * 128 + p0];
            const float4 w1 = *(const float4*)&wlds[(k4 * 4 + 1) * 128 + p0];
            const float4 w2 = *(const float4*)&wlds[(k4 * 4 + 2) * 128 + p0];
            const float4 w3 = *(const float4*)&wlds[(k4 * 4 + 3) * 128 + p0];
            acc0 = fmaf(x0, w0.x, acc0); acc1 = fmaf(x0, w0.y, acc1);
            acc2 = fmaf(x0, w0.z, acc2); acc3 = fmaf(x0, w0.w, acc3);
            acc0 = fmaf(x1, w1.x, acc0); acc1 = fmaf(x1, w1.y, acc1);
            acc2 = fmaf(x1, w1.z, acc2); acc3 = fmaf(x1, w1.w, acc3);
            acc0 = fmaf(x2, w2.x, acc0); acc1 = fmaf(x2, w2.y, acc1);
            acc2 = fmaf(x2, w2.z, acc2); acc3 = fmaf(x2, w2.w, acc3);
            acc0 = fmaf(x3, w3.x, acc0); acc1 = fmaf(x3, w3.y, acc1);
            acc2 = fmaf(x3, w3.z, acc2); acc3 = fmaf(x3, w3.w, acc3);
        }
        if (valid) {
            unsigned u0 = pack_bf16_pair(acc0, acc1);
            unsigned u1 = pack_bf16_pair(acc2, acc3);
            *(uint2*)&h1b[(size_t)node * 64 + 2 * l] = make_uint2(u0, u1);
            float vs0 = acc0 * aS[0] + acc2 * aS[2];   // head0
            float vs1 = acc1 * aS[1] + acc3 * aS[3];   // head1
            float vd0 = acc0 * aD[0] + acc2 * aD[2];
            float vd1 = acc1 * aD[1] + acc3 * aD[3];
#pragma unroll
            for (int off = 1; off < 32; off <<= 1) {
                vs0 += __shfl_xor(vs0, off);
                vs1 += __shfl_xor(vs1, off);
                vd0 += __shfl_xor(vd0, off);
                vd1 += __shfl_xor(vd1, off);
            }
            if (l == 0) {
                as1[node] = make_float2(vs0, vs1);
                ad1[node] = make_float2(vd0, vd1);
            }
        }
    }
}

// ---------------------------------------------------------------------------
// CSR build via two-level counting sort (no global atomics, L2-local writes).
// Coarse bucket = dst>>8 (NB buckets, NB<=256). Chunk = 8192 edges (NC chunks).
// osc[b*NC + c] = count of bucket-b edges in chunk c; exclusive-scanned
// bucket-major -> global placement offsets.
// ---------------------------------------------------------------------------
#define CHUNK 8192

__global__ __launch_bounds__(256) void chist_kernel(
    const int* __restrict__ dst, int E, int NB, int NC, int* __restrict__ osc)
{
    __shared__ int h[256];
    int tid = threadIdx.x, c = blockIdx.x;
    h[tid] = 0;
    __syncthreads();
    int e0 = c * CHUNK, e1 = min(e0 + CHUNK, E);
    for (int e = e0 + tid; e < e1; e += 256)
        atomicAdd(&h[dst[e] >> 8], 1);
    __syncthreads();
    if (tid < NB) osc[tid * NC + c] = h[tid];
}

// single-block exclusive scan, in place (len <= ~256K)
__global__ __launch_bounds__(1024) void oscan_kernel(int* __restrict__ osc, int len)
{
    __shared__ int wsum[16];
    int tid = threadIdx.x;
    int seg = (len + 1023) / 1024;
    int st = tid * seg, en = min(st + seg, len);
    int s = 0;
    for (int i = st; i < en; ++i) s += osc[i];
    int lane = tid & 63, w = tid >> 6;
    int incl = s;
#pragma unroll
    for (int off = 1; off < 64; off <<= 1) {
        int t = __shfl_up(incl, off);
        if (lane >= off) incl += t;
    }
    if (lane == 63) wsum[w] = incl;
    __syncthreads();
    int wb = 0;
    for (int i = 0; i < w; ++i) wb += wsum[i];
    int run = wb + incl - s;   // exclusive prefix of this thread's segment
    for (int i = st; i < en; ++i) { int v = osc[i]; osc[i] = run; run += v; }
}

// coarse scatter: place (src,dst) pairs grouped by coarse bucket
__global__ __launch_bounds__(256) void cscatter_kernel(
    const int* __restrict__ src, const int* __restrict__ dst,
    int E, int NB, int NC, const int* __restrict__ osc, int2* __restrict__ pairs)
{
    __shared__ int cur[256];
    int tid = threadIdx.x, c = blockIdx.x;
    if (tid < NB) cur[tid] = osc[tid * NC + c];
    __syncthreads();
    int e0 = c * CHUNK, e1 = min(e0 + CHUNK, E);
    for (int e = e0 + tid; e < e1; e += 256) {
        int d = dst[e];
        int p = atomicAdd(&cur[d >> 8], 1);
        pairs[p] = make_int2(src[e], d);
    }
}

// fine sort within each coarse bucket: emits row_start and csr_src.
// One block per bucket; all writes land in an L2-resident ~32KB region.
__global__ __launch_bounds__(256) void fsort_kernel(
    const int2* __restrict__ pairs, const int* __restrict__ osc,
    int E, int n, int NB, int NC,
    int* __restrict__ row_start, int* __restrict__ csr_src)
{
    __shared__ int fh[256];
    __shared__ int cur[256];
    __shared__ int wsum[4];
    int tid = threadIdx.x, b = blockIdx.x;
    int rbase = osc[b * NC];
    int rend  = (b + 1 < NB) ? osc[(b + 1) * NC] : E;
    fh[tid] = 0;
    __syncthreads();
    for (int i = rbase + tid; i < rend; i += 256)
        atomicAdd(&fh[pairs[i].y & 255], 1);
    __syncthreads();
    // exclusive scan of fh[256]
    int v = fh[tid];
    int lane = tid & 63, w = tid >> 6;
    int incl = v;
#pragma unroll
    for (int off = 1; off < 64; off <<= 1) {
        int t = __shfl_up(incl, off);
        if (lane >= off) incl += t;
    }
    if (lane == 63) wsum[w] = incl;
    __syncthreads();
    int wb = 0;
    for (int i = 0; i < w; ++i) wb += wsum[i];
    int excl = wb + incl - v;
    int node = b * 256 + tid;
    if (node < n) row_start[node] = rbase + excl;
    cur[tid] = rbase + excl;
    __syncthreads();
    for (int i = rbase + tid; i < rend; i += 256) {
        int2 pr = pairs[i];
        int p = atomicAdd(&cur[pr.y & 255], 1);
        csr_src[p] = pr.x;
    }
    if (b == 0 && tid == 0) row_start[n] = E;
}

// ---------------------------------------------------------------------------
// Layer-1 gather: one wave per node, chunked online softmax (unchanged).
// ---------------------------------------------------------------------------
__global__ __launch_bounds__(256) void gather1_kernel(
    const unsigned* __restrict__ h1b, const float2* __restrict__ as1, const float2* __restrict__ ad1,
    const int* __restrict__ row_start, const int* __restrict__ csr_src,
    const float* __restrict__ b1, const float* __restrict__ W2,
    float* __restrict__ h2, int n)
{
    int wid = threadIdx.x >> 6, lane = threadIdx.x & 63;
    int v = blockIdx.x * 4 + wid;
    if (v >= n) return;

    float2 ad = ad1[v];
    float2 asv = as1[v];
    float m0 = leaky(asv.x + ad.x), m1 = leaky(asv.y + ad.y);   // self-loop logit
    float s0 = 1.f, s1 = 1.f;
    unsigned su = h1b[(size_t)v * 64 + lane];
    float acc0 = __uint_as_float(su << 16);          // head0 (channel = lane)
    float acc1 = __uint_as_float(su & 0xffff0000u);  // head1

    int t0 = row_start[v], t1 = row_start[v + 1];
    for (int t = t0; t < t1; t += 64) {
        int nv = t1 - t; if (nv > 64) nv = 64;
        int srcn = v;
        float e0 = -INFINITY, e1 = -INFINITY;
        if (lane < nv) {
            srcn = csr_src[t + lane];
            float2 as = as1[srcn];
            e0 = leaky(as.x + ad.x);
            e1 = leaky(as.y + ad.y);
        }
        float c0 = e0, c1 = e1;
#pragma unroll
        for (int off = 32; off >= 1; off >>= 1) {
            c0 = fmaxf(c0, __shfl_xor(c0, off));
            c1 = fmaxf(c1, __shfl_xor(c1, off));
        }
        float nm0 = fmaxf(m0, c0), nm1 = fmaxf(m1, c1);
        float r0 = __expf(m0 - nm0), r1 = __expf(m1 - nm1);
        acc0 *= r0; acc1 *= r1; s0 *= r0; s1 *= r1;
        m0 = nm0; m1 = nm1;
        float p0 = __expf(e0 - m0), p1 = __expf(e1 - m1);   // -inf -> 0 for masked lanes
        float q0 = p0, q1 = p1;
#pragma unroll
        for (int off = 32; off >= 1; off >>= 1) {
            q0 += __shfl_xor(q0, off);
            q1 += __shfl_xor(q1, off);
        }
        s0 += q0; s1 += q1;
        for (int j = 0; j < nv; ++j) {
            int sj   = __shfl(srcn, j);
            float w0 = __shfl(p0, j);
            float w1 = __shfl(p1, j);
            unsigned hu = h1b[(size_t)sj * 64 + lane];
            acc0 = fmaf(w0, __uint_as_float(hu << 16), acc0);
            acc1 = fmaf(w1, __uint_as_float(hu & 0xffff0000u), acc1);
        }
    }
    float o0 = acc0 / (s0 + 1e-16f) + b1[lane];        // head0, channel=lane
    float o1 = acc1 / (s1 + 1e-16f) + b1[64 + lane];   // head1
    o0 = fmaxf(o0, 0.f);
    o1 = fmaxf(o1, 0.f);
    float hv = o0 * W2[lane] + o1 * W2[64 + lane];
#pragma unroll
    for (int off = 1; off < 64; off <<= 1) hv += __shfl_xor(hv, off);
    if (lane == 0) h2[v] = hv;
}

// ---------------------------------------------------------------------------
// Layer-2 gather: one thread per node (scalar head), online softmax + sigmoid.
// ---------------------------------------------------------------------------
__global__ void gather2_kernel(
    const float* __restrict__ h2, const int* __restrict__ row_start, const int* __restrict__ csr_src,
    const float* __restrict__ aS2, const float* __restrict__ aD2, const float* __restrict__ b2,
    float* __restrict__ out, int n)
{
    int v = blockIdx.x * 256 + threadIdx.x;
    if (v >= n) return;
    float as2 = aS2[0], ad2c = aD2[0];
    float hv = h2[v];
    float ad = hv * ad2c;
    float e = leaky(hv * as2 + ad);
    float m = e, s = 1.f, num = hv;
    int t1 = row_start[v + 1];
    for (int t = row_start[v]; t < t1; ++t) {
        int srcn = csr_src[t];
        float hsv = h2[srcn];
        float en = leaky(hsv * as2 + ad);
        if (en > m) { float c = __expf(m - en); s *= c; num *= c; m = en; }
        float p = __expf(en - m);
        s += p;
        num = fmaf(p, hsv, num);
    }
    float o = num / (s + 1e-16f) + b2[0];
    out[v] = 1.f / (1.f + __expf(-o));
}

// ---------------------------------------------------------------------------
extern "C" void kernel_launch(void* const* d_in, const int* in_sizes, int n_in,
                              void* d_out, int out_size, void* d_ws, size_t ws_size,
                              hipStream_t stream)
{
    const float* x      = (const float*)d_in[0];
    const int*   eidx   = (const int*)  d_in[1];
    const float* W1     = (const float*)d_in[2];
    const float* a_src1 = (const float*)d_in[3];
    const float* a_dst1 = (const float*)d_in[4];
    const float* b1     = (const float*)d_in[5];
    const float* W2     = (const float*)d_in[6];
    const float* a_src2 = (const float*)d_in[7];
    const float* a_dst2 = (const float*)d_in[8];
    const float* b2     = (const float*)d_in[9];

    int n = in_sizes[0] / 128;
    int E = in_sizes[1] / 2;
    const int* src = eidx;
    const int* dst = eidx + E;

    int NC = (E + CHUNK - 1) / CHUNK;   // 196 for E=1.6M
    int NB = (n + 255) / 256;           // 196 for n=50000 (must be <=256)

    char* ws = (char*)d_ws;
    size_t off = 0;
    auto alloc = [&](size_t bytes) { size_t o = off; off += (bytes + 255) & ~(size_t)255; return o; };

    unsigned* h1b    = (unsigned*)(ws + alloc((size_t)n * 64 * 4));   // 12.8 MB
    float2* as1     = (float2*)(ws + alloc((size_t)n * 8));
    float2* ad1     = (float2*)(ws + alloc((size_t)n * 8));
    float*  h2      = (float*) (ws + alloc((size_t)n * 4));
    int*    rowst   = (int*)   (ws + alloc((size_t)(n + 1) * 4));
    int*    osc     = (int*)   (ws + alloc((size_t)NB * NC * 4));     // 153 KB
    int2*   pairs   = (int2*)  (ws + alloc((size_t)E * 8));           // 12.8 MB
    int*    csr_src = (int*)   (ws + alloc((size_t)E * 4));           // 6.4 MB
    (void)ws_size; (void)n_in; (void)out_size;

    gemm1_kernel<<<1024, 256, 0, stream>>>(x, W1, a_src1, a_dst1, h1b, as1, ad1, n);

    chist_kernel<<<NC, 256, 0, stream>>>(dst, E, NB, NC, osc);
    oscan_kernel<<<1, 1024, 0, stream>>>(osc, NB * NC);
    cscatter_kernel<<<NC, 256, 0, stream>>>(src, dst, E, NB, NC, osc, pairs);
    fsort_kernel<<<NB, 256, 0, stream>>>(pairs, osc, E, n, NB, NC, rowst, csr_src);

    gather1_kernel<<<(n + 3) / 4, 256, 0, stream>>>(h1b, as1, ad1, rowst, csr_src, b1, W2, h2, n);
    gather2_kernel<<<(n + 255) / 256, 256, 0, stream>>>(h2, rowst, csr_src, a_src2, a_dst2, b2,
                                                        (float*)d_out, n);
}